// Round 1
// baseline (224.996 us; speedup 1.0000x reference)
//
#include <hip/hip_runtime.h>
#include <hip/hip_bf16.h>

typedef __attribute__((ext_vector_type(8))) short bf16x8;
typedef __attribute__((ext_vector_type(4))) float f32x4;

#define NH 16
#define DM 1024
#define HD 64
#define CSEQ 2048
#define MROWS 8192   // B*C
#define NBH 64       // B*NH

static __device__ __forceinline__ unsigned short f2bf(float f) {
  __hip_bfloat16 h = __float2bfloat16(f);
  return *reinterpret_cast<unsigned short*>(&h);
}

static __device__ __forceinline__ short bf_qscale(short s) {
  // fold attn scale (1/8) and log2(e) into Q: S*0.125*1.4427 -> exp2 domain
  unsigned u = ((unsigned)(unsigned short)s) << 16;
  float f = __builtin_bit_cast(float, u) * 0.18033688f;
  return (short)f2bf(f);
}

static __device__ __forceinline__ void gload_lds16(const void* g, void* l) {
  __builtin_amdgcn_global_load_lds(
      (const __attribute__((address_space(1))) unsigned int*)g,
      (__attribute__((address_space(3))) unsigned int*)l, 16, 0, 0);
}

// ---------------- cast fp32 -> bf16 (vectorized x4) ----------------
__global__ __launch_bounds__(256) void cast_f32_bf16(const float* __restrict__ in,
                                                     unsigned short* __restrict__ out,
                                                     int n4) {
  int stride = gridDim.x * blockDim.x;
  for (int i = blockIdx.x * blockDim.x + threadIdx.x; i < n4; i += stride) {
    float4 v = ((const float4*)in)[i];
    ushort4 o;
    o.x = f2bf(v.x); o.y = f2bf(v.y); o.z = f2bf(v.z); o.w = f2bf(v.w);
    ((ushort4*)out)[i] = o;
  }
}

// ---------------- transpose + cast: src[K][N] fp32 -> dst[N][K] bf16 ----------------
__global__ __launch_bounds__(256) void transpose_cast(const float* __restrict__ src,
                                                      unsigned short* __restrict__ dst,
                                                      int K, int N) {
  __shared__ float tile[32][33];
  int tx = threadIdx.x, ty = threadIdx.y;
  int n0 = blockIdx.x * 32, k0 = blockIdx.y * 32;
  #pragma unroll
  for (int i = 0; i < 32; i += 8)
    tile[ty + i][tx] = src[(size_t)(k0 + ty + i) * N + n0 + tx];
  __syncthreads();
  #pragma unroll
  for (int i = 0; i < 32; i += 8)
    dst[(size_t)(n0 + ty + i) * K + k0 + tx] = f2bf(tile[tx][ty + i]);
}

// ===================== 256x256 8-phase bf16 GEMM =====================
// C = A[M][K] * BT[N][K]^T + bias.  8 waves (2Mx4N), per-wave 128x64 out,
// BK=64, double-buffered 128KB LDS, counted vmcnt (never 0 in main loop),
// XOR-swizzled LDS rows (slot ^ (row&7)), setprio around MFMA clusters.
// MODE 0: write fp32 out[M][N].
// MODE 1: scatter bf16 into Q,K [bh][cq][d]; V transposed+kappa-permuted.

static __device__ __forceinline__ void stage_half(const unsigned short* s0,
                                                  const unsigned short* s1,
                                                  char* dst, int c0, int c1) {
  gload_lds16(s0, dst + c0 * 16);
  gload_lds16(s1, dst + c1 * 16);
}

template<int CNT>
static __device__ __forceinline__ void ld_frags(const char* base, int r0, int cx, int g,
                                                bf16x8 (*out)[2]) {
  #pragma unroll
  for (int i = 0; i < CNT; i++) {
    int row = r0 + i * 16 + cx;
    #pragma unroll
    for (int kc = 0; kc < 2; kc++)
      out[i][kc] = *(const bf16x8*)(base + row * 128 + ((((kc << 2) | g) ^ (row & 7)) << 4));
  }
}

static __device__ __forceinline__ void mfma_q(const bf16x8 af[4][2], const bf16x8 bfr[2][2],
                                              f32x4 acc[8][4], int qm, int qn) {
  #pragma unroll
  for (int kc = 0; kc < 2; kc++)
    #pragma unroll
    for (int mi = 0; mi < 4; mi++)
      #pragma unroll
      for (int ni = 0; ni < 2; ni++)
        acc[qm * 4 + mi][qn * 2 + ni] = __builtin_amdgcn_mfma_f32_16x16x32_bf16(
            af[mi][kc], bfr[ni][kc], acc[qm * 4 + mi][qn * 2 + ni], 0, 0, 0);
}

#define BARR() __builtin_amdgcn_s_barrier()
#define LGKM0() asm volatile("s_waitcnt lgkmcnt(0)" ::: "memory")
#define PRIO1() __builtin_amdgcn_s_setprio(1)
#define PRIO0() __builtin_amdgcn_s_setprio(0)

template<int MODE>
__global__ __launch_bounds__(512, 2) void gemm256(const unsigned short* __restrict__ A,
                                                  const unsigned short* __restrict__ BT,
                                                  const float* __restrict__ bias,
                                                  float* __restrict__ outF,
                                                  unsigned short* __restrict__ outQKV,
                                                  int N, int K) {
  __shared__ char sA[2][32768];   // [256 rows][64 k] bf16, rows 128B, slot^(row&7) swizzle
  __shared__ char sB[2][32768];
  int tid = threadIdx.x;
  int w = tid >> 6, l = tid & 63, g = l >> 4, cx = l & 15;
  int wm = (w >> 2) * 128, wn = (w & 3) * 64;

  // XCD-aware bijective swizzle (nwg % 8 == 0 for both launch shapes)
  int nwgx = gridDim.x;
  int nwg = nwgx * gridDim.y;
  int gid = blockIdx.y * nwgx + blockIdx.x;
  int swz = (gid & 7) * (nwg >> 3) + (gid >> 3);
  int bm = (swz / nwgx) * 256, bn = (swz % nwgx) * 256;

  // staging: pre-swizzled global source, linear LDS dest (DMA = uniform base + lane*16)
  int c0 = tid, c1 = tid + 512;
  int ar0 = c0 >> 3, as0 = ((c0 & 7) ^ (ar0 & 7)) * 8;
  int ar1 = c1 >> 3, as1 = ((c1 & 7) ^ (ar1 & 7)) * 8;
  const unsigned short* Ap0 = A + (size_t)(bm + ar0) * K + as0;
  const unsigned short* Ap1 = A + (size_t)(bm + ar1) * K + as1;
  const unsigned short* Bp0 = BT + (size_t)(bn + ar0) * K + as0;
  const unsigned short* Bp1 = BT + (size_t)(bn + ar1) * K + as1;
  const size_t HS = (size_t)128 * K;   // half-tile (128 rows) offset in elements

  f32x4 acc[8][4];
  #pragma unroll
  for (int i = 0; i < 8; i++)
    #pragma unroll
    for (int j = 0; j < 4; j++) acc[i][j] = (f32x4){0.f, 0.f, 0.f, 0.f};

  int NT = K >> 6;   // K-tiles of 64 (>= 2 for all shapes here)

  // prologue: tile0 fully + tile1.A0 left in flight
  stage_half(Ap0,      Ap1,      sA[0],         c0, c1);   // t0.A0
  stage_half(Ap0 + HS, Ap1 + HS, sA[0] + 16384, c0, c1);   // t0.A1
  stage_half(Bp0,      Bp1,      sB[0],         c0, c1);   // t0.B0
  stage_half(Bp0 + HS, Bp1 + HS, sB[0] + 16384, c0, c1);   // t0.B1
  stage_half(Ap0 + 64, Ap1 + 64, sA[1],         c0, c1);   // t1.A0 (stays in flight)
  asm volatile("s_waitcnt vmcnt(2)" ::: "memory");
  BARR();

  int cur = 0;
  for (int t = 0; t < NT; t++) {
    const char* Ac = sA[cur];
    const char* Bc = sB[cur];
    char* An = sA[cur ^ 1];
    char* Bn = sB[cur ^ 1];
    int kn  = (t + 1) << 6;
    int kn2 = (t + 2) << 6;
    bool h1 = (t + 1) < NT, h2 = (t + 2) < NT;
    bf16x8 af[4][2], bfr[2][2];

    // ---- P0: quadrant (qm0,qn0) ----
    ld_frags<4>(Ac, wm, cx, g, af);
    ld_frags<2>(Bc, wn, cx, g, bfr);
    if (h1) stage_half(Ap0 + HS + kn, Ap1 + HS + kn, An + 16384, c0, c1);  // t+1.A1
    BARR(); LGKM0();
    PRIO1(); mfma_q(af, bfr, acc, 0, 0); PRIO0();
    BARR();

    // ---- P1: (qm0,qn1), reuse af ----
    ld_frags<2>(Bc, wn + 32, cx, g, bfr);
    if (h1) stage_half(Bp0 + kn, Bp1 + kn, Bn, c0, c1);                    // t+1.B0
    BARR(); LGKM0();
    PRIO1(); mfma_q(af, bfr, acc, 0, 1); PRIO0();
    BARR();

    // ---- P2: (qm1,qn0) ----
    ld_frags<4>(Ac, wm + 64, cx, g, af);
    ld_frags<2>(Bc, wn, cx, g, bfr);
    if (h1) stage_half(Bp0 + HS + kn, Bp1 + HS + kn, Bn + 16384, c0, c1);  // t+1.B1
    BARR(); LGKM0();
    PRIO1(); mfma_q(af, bfr, acc, 1, 0); PRIO0();
    BARR();

    // ---- P3: (qm1,qn1) ----
    ld_frags<2>(Bc, wn + 32, cx, g, bfr);
    BARR(); LGKM0();
    // cur.A0's last reads (P2) are globally complete at this barrier -> safe
    // to DMA tile t+2's A0 into the buffer being retired this tile.
    if (h2) stage_half(Ap0 + kn2, Ap1 + kn2, sA[cur], c0, c1);             // t+2.A0
    PRIO1(); mfma_q(af, bfr, acc, 1, 1); PRIO0();
    if (h1) {
      if (h2) { asm volatile("s_waitcnt vmcnt(2)" ::: "memory"); }  // t+1 landed, t+2.A0 in flight
      else    { asm volatile("s_waitcnt vmcnt(0)" ::: "memory"); }  // final boundary only
    }
    BARR();
    cur ^= 1;
  }

  // epilogue: C/D layout row=(l>>4)*4+r (m-side), col=l&15 (n-side)
  #pragma unroll
  for (int ai = 0; ai < 8; ai++) {
    #pragma unroll
    for (int aj = 0; aj < 4; aj++) {
      int col = bn + wn + aj * 16 + cx;
      float bv = bias[col];
      int row0 = bm + wm + ai * 16 + g * 4;
      #pragma unroll
      for (int r = 0; r < 4; r++) {
        float v = acc[ai][aj][r] + bv;
        int rr = row0 + r;
        if (MODE == 0) {
          outF[(size_t)rr * N + col] = v;
        } else {
          int which = col >> 10, rem = col & 1023;
          int h = rem >> 6, d = rem & 63;
          int b = rr >> 11, cq = rr & 2047;
          if (which == 2) {
            // V: store transposed + kappa-permuted (pure within-32 permutation)
            int pos = (cq & ~31) + (((cq >> 2) & 3) << 3) + (((cq >> 4) & 1) << 2) + (cq & 3);
            outQKV[((size_t)2 * NBH + b * NH + h) * (CSEQ * HD) +
                   (size_t)d * CSEQ + pos] = f2bf(v);
          } else {
            outQKV[((size_t)which * NBH + b * NH + h) * (CSEQ * HD) + (size_t)cq * HD + d] = f2bf(v);
          }
        }
      }
    }
  }
}

// ---------------- flash attention (causal), swapped-QK^T, register-P ----------------
// 8 waves x 16 q-rows (QBLK=128), KVBLK=128, dbuf, one barrier/iter, XCD-aware
// remap, exp2 softmax, defer-max, global_load_lds DMA staging.
__global__ __launch_bounds__(512, 4) void attn_kernel(const unsigned short* __restrict__ Qb,
                                                      const unsigned short* __restrict__ Kb,
                                                      const unsigned short* __restrict__ VTb,
                                                      unsigned short* __restrict__ O) {
  __shared__ char sKb[2][16384]; // K [128 k][64 d] bf16: slot sp of row holds d-slot sp^(row&7)
  __shared__ char sVt[2][16384]; // V^T [64 d][128 pos] bf16: slot sp of row d holds pos-slot sp^(d&7)
  int tid = threadIdx.x;
  int w = tid >> 6, l = tid & 63, g = l >> 4, cx = l & 15;
  // XCD-aware decode: g%8 == bh&7 -> all 16 qt-blocks of a bh land on one XCD,
  // dispatched consecutively (qt=15 first within each bh for LPT balance).
  int gid = blockIdx.x;
  int bh = ((gid >> 7) << 3) | (gid & 7);
  int qt = 15 - ((gid >> 3) & 15);

  const unsigned short* Qp  = Qb  + (size_t)bh * CSEQ * HD;
  const unsigned short* Kp  = Kb  + (size_t)bh * CSEQ * HD;
  const unsigned short* VTp = VTb + (size_t)bh * CSEQ * HD;  // [64 d][2048 k']

  // Q fragments (B-operand: col=lane&15=q, k=(lane>>4)*8+j), pre-scaled to exp2 domain
  int qrow = qt * 128 + w * 16 + cx;
  bf16x8 qf[2];
  qf[0] = *(const bf16x8*)(Qp + (size_t)qrow * HD + g * 8);
  qf[1] = *(const bf16x8*)(Qp + (size_t)qrow * HD + 32 + g * 8);
  #pragma unroll
  for (int kc = 0; kc < 2; kc++)
    #pragma unroll
    for (int j = 0; j < 8; j++) qf[kc][j] = bf_qscale(qf[kc][j]);

  f32x4 o[4];
  #pragma unroll
  for (int nf2 = 0; nf2 < 4; nf2++) o[nf2] = (f32x4){0.f, 0.f, 0.f, 0.f};
  float mrow = -INFINITY, lrow = 0.f;

  // staging constants (pre-swizzled global source, linear LDS dest)
  int c0 = tid, c1 = tid + 512;
  int krow0 = c0 >> 3, ksl0 = (c0 & 7) ^ (krow0 & 7);
  int krow1 = c1 >> 3, ksl1 = (c1 & 7) ^ (krow1 & 7);
  int vd0 = c0 >> 4, vsl0 = (c0 & 15) ^ (vd0 & 7);
  int vd1 = c1 >> 4, vsl1 = (c1 & 15) ^ (vd1 & 7);
  const unsigned short* Ksrc0 = Kp + (size_t)krow0 * HD + ksl0 * 8;   // += kt*8192
  const unsigned short* Ksrc1 = Kp + (size_t)krow1 * HD + ksl1 * 8;
  const unsigned short* Vsrc0 = VTp + (size_t)vd0 * CSEQ + vsl0 * 8;  // += kt*128
  const unsigned short* Vsrc1 = VTp + (size_t)vd1 * CSEQ + vsl1 * 8;

  // prologue: DMA tile 0 into buf0
  gload_lds16(Ksrc0, sKb[0] + c0 * 16);
  gload_lds16(Ksrc1, sKb[0] + c1 * 16);
  gload_lds16(Vsrc0, sVt[0] + c0 * 16);
  gload_lds16(Vsrc1, sVt[0] + c1 * 16);
  __syncthreads();
  int cur = 0;

  for (int kt = 0; kt <= qt; kt++) {
    if (kt < qt) {  // DMA next tile into buf^1; lands under compute below
      size_t ko = (size_t)(kt + 1) * 128 * HD;
      size_t vo = (size_t)(kt + 1) * 128;
      gload_lds16(Ksrc0 + ko, sKb[cur ^ 1] + c0 * 16);
      gload_lds16(Ksrc1 + ko, sKb[cur ^ 1] + c1 * 16);
      gload_lds16(Vsrc0 + vo, sVt[cur ^ 1] + c0 * 16);
      gload_lds16(Vsrc1 + vo, sVt[cur ^ 1] + c1 * 16);
    }
    const char* Kc = sKb[cur];
    const char* Vc = sVt[cur];

    // ---- S^T = K * Q^T : A = K rows (m = kv idx), B = Q (n = q) ----
    f32x4 sacc[8];
    #pragma unroll
    for (int nf = 0; nf < 8; nf++) sacc[nf] = (f32x4){0.f, 0.f, 0.f, 0.f};
    __builtin_amdgcn_s_setprio(1);
    #pragma unroll
    for (int kc = 0; kc < 2; kc++) {
      #pragma unroll
      for (int nf = 0; nf < 8; nf++) {
        int row = nf * 16 + cx;
        bf16x8 kf = *(const bf16x8*)(Kc + row * 128 + ((((kc << 2) | g) ^ (row & 7)) << 4));
        sacc[nf] = __builtin_amdgcn_mfma_f32_16x16x32_bf16(kf, qf[kc], sacc[nf], 0, 0, 0);
      }
    }
    __builtin_amdgcn_s_setprio(0);

    // lane (g,cx) holds S2[q = w*16+cx][k_local = nf*16 + 4g + r]  (log2 domain)
    if (kt == qt) {  // uniform branch: mask only the diagonal tile
      #pragma unroll
      for (int nf = 0; nf < 8; nf++)
        #pragma unroll
        for (int r = 0; r < 4; r++)
          if (nf * 16 + 4 * g + r > w * 16 + cx) sacc[nf][r] = -INFINITY;
    }
    // 5-deep tree max
    float m8[8];
    #pragma unroll
    for (int nf = 0; nf < 8; nf++)
      m8[nf] = fmaxf(fmaxf(sacc[nf][0], sacc[nf][1]), fmaxf(sacc[nf][2], sacc[nf][3]));
    float mx = fmaxf(fmaxf(fmaxf(m8[0], m8[1]), fmaxf(m8[2], m8[3])),
                     fmaxf(fmaxf(m8[4], m8[5]), fmaxf(m8[6], m8[7])));
    mx = fmaxf(mx, __shfl_xor(mx, 16));
    mx = fmaxf(mx, __shfl_xor(mx, 32));

    // defer-max (T13): skip rescale when per-tile growth <= 8 (p <= 2^8)
    if (!__all(mx - mrow <= 8.f)) {
      float mnew = fmaxf(mrow, mx);
      float alpha = __builtin_amdgcn_exp2f(mrow - mnew);
      mrow = mnew;
      lrow *= alpha;
      #pragma unroll
      for (int r = 0; r < 4; r++) {
        float ar = __shfl(alpha, (l & 48) | ((l >> 2) & 12) | r);
        #pragma unroll
        for (int nf2 = 0; nf2 < 4; nf2++) o[nf2][r] *= ar;
      }
    }
    #pragma unroll
    for (int nf = 0; nf < 8; nf++)
      #pragma unroll
      for (int r = 0; r < 4; r++)
        sacc[nf][r] = __builtin_amdgcn_exp2f(sacc[nf][r] - mrow);
    // 5-deep tree sum
    float s8[8];
    #pragma unroll
    for (int nf = 0; nf < 8; nf++)
      s8[nf] = (sacc[nf][0] + sacc[nf][1]) + (sacc[nf][2] + sacc[nf][3]);
    float sum = ((s8[0] + s8[1]) + (s8[2] + s8[3])) + ((s8[4] + s8[5]) + (s8[6] + s8[7]));
    sum += __shfl_xor(sum, 16);
    sum += __shfl_xor(sum, 32);
    lrow += sum;

    // P -> bf16 A-frags; kc=0..3: elem j carries k = 32kc + 16*(j>=4) + 4g + (j&3)
    bf16x8 pa[4];
    #pragma unroll
    for (int kc = 0; kc < 4; kc++) {
      #pragma unroll
      for (int j = 0; j < 4; j++) {
        pa[kc][j]     = (short)f2bf(sacc[2 * kc][j]);
        pa[kc][j + 4] = (short)f2bf(sacc[2 * kc + 1][j]);
      }
    }

    // ---- O += P * V : B-frag from kappa-ordered V^T rows (contiguous 16B) ----
    __builtin_amdgcn_s_setprio(1);
    #pragma unroll
    for (int kc = 0; kc < 4; kc++) {
      #pragma unroll
      for (int nf2 = 0; nf2 < 4; nf2++) {
        int d = nf2 * 16 + cx;
        bf16x8 vf = *(const bf16x8*)(Vc + ((d * 256 + (((kc << 2) | g) << 4)) ^ ((d & 7) << 4)));
        o[nf2] = __builtin_amdgcn_mfma_f32_16x16x32_bf16(pa[kc], vf, o[nf2], 0, 0, 0);
      }
    }
    __builtin_amdgcn_s_setprio(0);

    if (kt < qt) {   // single barrier per iter: drains this wave's DMAs + LDS reads
      __syncthreads();
      cur ^= 1;
    }
  }

  // epilogue: lane (g,cx): O rows q = 4g+r, cols d = nf2*16+cx
  int b = bh >> 4, h = bh & 15;
  float linv = 1.0f / lrow;
  #pragma unroll
  for (int r = 0; r < 4; r++) {
    float inv = __shfl(linv, (l & 48) | ((l >> 2) & 12) | r);
    int q = qt * 128 + w * 16 + 4 * g + r;
    size_t base = ((size_t)(b * CSEQ + q)) * DM + h * HD;
    #pragma unroll
    for (int nf2 = 0; nf2 < 4; nf2++)
      O[base + nf2 * 16 + cx] = f2bf(o[nf2][r] * inv);
  }
}

// ---------------- launch ----------------
extern "C" void kernel_launch(void* const* d_in, const int* in_sizes, int n_in,
                              void* d_out, int out_size, void* d_ws, size_t ws_size,
                              hipStream_t stream) {
  const float* x    = (const float*)d_in[0];
  const float* Wqkv = (const float*)d_in[1];
  const float* bqkv = (const float*)d_in[2];
  const float* Wo   = (const float*)d_in[3];
  const float* bo   = (const float*)d_in[4];
  float* out = (float*)d_out;

  unsigned short* ws = (unsigned short*)d_ws;
  const size_t XB_OFF    = 0;                     // x bf16 [8192][1024]
  const size_t WQKVT_OFF = 8388608;               // Wqkv^T bf16 [3072][1024]
  const size_t WOT_OFF   = WQKVT_OFF + 3145728;   // Wo^T bf16 [1024][1024]
  const size_t QKV_OFF   = WOT_OFF + 1048576;     // Q,K [bh][k][d]; V^T [bh][d][k']
  const size_t ATT_OFF   = QKV_OFF + 3 * 8388608; // att out bf16 [8192][1024]

  unsigned short* xb    = ws + XB_OFF;
  unsigned short* wqkvT = ws + WQKVT_OFF;
  unsigned short* woT   = ws + WOT_OFF;
  unsigned short* qkv   = ws + QKV_OFF;
  unsigned short* att   = ws + ATT_OFF;

  cast_f32_bf16<<<2048, 256, 0, stream>>>(x, xb, (MROWS * DM) / 4);
  transpose_cast<<<dim3(3 * DM / 32, DM / 32), dim3(32, 8), 0, stream>>>(Wqkv, wqkvT, DM, 3 * DM);
  transpose_cast<<<dim3(DM / 32, DM / 32), dim3(32, 8), 0, stream>>>(Wo, woT, DM, DM);

  gemm256<1><<<dim3(3 * DM / 256, MROWS / 256), 512, 0, stream>>>(
      xb, wqkvT, bqkv, nullptr, qkv, 3 * DM, DM);

  attn_kernel<<<dim3(1024), 512, 0, stream>>>(
      qkv, qkv + 8388608, qkv + 16777216, att);

  gemm256<0><<<dim3(DM / 256, MROWS / 256), 512, 0, stream>>>(
      att, woT, bo, out, nullptr, DM, DM);
}

// Round 2
// 201.408 us; speedup vs baseline: 1.1171x; 1.1171x over previous
//
#include <hip/hip_runtime.h>
#include <hip/hip_bf16.h>

typedef __attribute__((ext_vector_type(8))) short bf16x8;
typedef __attribute__((ext_vector_type(4))) float f32x4;

#define NH 16
#define DM 1024
#define HD 64
#define CSEQ 2048
#define MROWS 8192   // B*C
#define NBH 64       // B*NH

static __device__ __forceinline__ unsigned short f2bf(float f) {
  __hip_bfloat16 h = __float2bfloat16(f);
  return *reinterpret_cast<unsigned short*>(&h);
}

static __device__ __forceinline__ short bf_qscale(short s) {
  // fold attn scale (1/8) and log2(e) into Q: S*0.125*1.4427 -> exp2 domain
  unsigned u = ((unsigned)(unsigned short)s) << 16;
  float f = __builtin_bit_cast(float, u) * 0.18033688f;
  return (short)f2bf(f);
}

static __device__ __forceinline__ void gload_lds16(const void* g, void* l) {
  __builtin_amdgcn_global_load_lds(
      (const __attribute__((address_space(1))) unsigned int*)g,
      (__attribute__((address_space(3))) unsigned int*)l, 16, 0, 0);
}

// ---------------- cast fp32 -> bf16 (vectorized x4) ----------------
__global__ __launch_bounds__(256) void cast_f32_bf16(const float* __restrict__ in,
                                                     unsigned short* __restrict__ out,
                                                     int n4) {
  int stride = gridDim.x * blockDim.x;
  for (int i = blockIdx.x * blockDim.x + threadIdx.x; i < n4; i += stride) {
    float4 v = ((const float4*)in)[i];
    ushort4 o;
    o.x = f2bf(v.x); o.y = f2bf(v.y); o.z = f2bf(v.z); o.w = f2bf(v.w);
    ((ushort4*)out)[i] = o;
  }
}

// ---------------- transpose + cast: src[K][N] fp32 -> dst[N][K] bf16 ----------------
__global__ __launch_bounds__(256) void transpose_cast(const float* __restrict__ src,
                                                      unsigned short* __restrict__ dst,
                                                      int K, int N) {
  __shared__ float tile[32][33];
  int tx = threadIdx.x, ty = threadIdx.y;
  int n0 = blockIdx.x * 32, k0 = blockIdx.y * 32;
  #pragma unroll
  for (int i = 0; i < 32; i += 8)
    tile[ty + i][tx] = src[(size_t)(k0 + ty + i) * N + n0 + tx];
  __syncthreads();
  #pragma unroll
  for (int i = 0; i < 32; i += 8)
    dst[(size_t)(n0 + ty + i) * K + k0 + tx] = f2bf(tile[tx][ty + i]);
}

// ===================== 256x128 2-phase-per-tile bf16 GEMM =====================
// C = A[M][K] * BT[N][K]^T + bias.  8 waves (4Mx2N), per-wave 64x64 out, BK=64,
// double-buffered 96KB LDS, counted vmcnt (never 0 until final boundary),
// XOR-swizzled LDS rows (slot ^ (row&7)), setprio around MFMA clusters.
// Per K-tile per wave: 16 ds_read_b128 (minimum: all frags loaded once) +
// 32 MFMA split into 2 phases of 16.  Staging per tile: t+1.B at P0 (into the
// free dbuf half), t+2.A at P1 (into the just-retired A buffer); boundary wait
// vmcnt(4) keeps one full A-tile (4 loads) in flight across every boundary.
// Grid geometry: QKV 24x32=768 blocks (3 exact rounds of 256 CUs),
// proj 8x32=256 blocks (1 exact round) -- no partial-round tail.
// MODE 0: write fp32 out[M][N].
// MODE 1: scatter bf16 into Q,K [bh][cq][d]; V transposed+kappa-permuted.

template<int CNT>
static __device__ __forceinline__ void ld_frags(const char* base, int r0, int cx, int g,
                                                bf16x8 (*out)[2]) {
  #pragma unroll
  for (int i = 0; i < CNT; i++) {
    int row = r0 + i * 16 + cx;
    #pragma unroll
    for (int kc = 0; kc < 2; kc++)
      out[i][kc] = *(const bf16x8*)(base + row * 128 + ((((kc << 2) | g) ^ (row & 7)) << 4));
  }
}

static __device__ __forceinline__ void mfma_pair(const bf16x8 af[4][2], const bf16x8 bf2[2][2],
                                                 f32x4 acc[4][4], int n0) {
  #pragma unroll
  for (int kc = 0; kc < 2; kc++)
    #pragma unroll
    for (int mi = 0; mi < 4; mi++)
      #pragma unroll
      for (int ni = 0; ni < 2; ni++)
        acc[mi][n0 + ni] = __builtin_amdgcn_mfma_f32_16x16x32_bf16(
            af[mi][kc], bf2[ni][kc], acc[mi][n0 + ni], 0, 0, 0);
}

#define BARR() __builtin_amdgcn_s_barrier()
#define LGKM0() asm volatile("s_waitcnt lgkmcnt(0)" ::: "memory")
#define VMCNT4() asm volatile("s_waitcnt vmcnt(4)" ::: "memory")
#define VMCNT0() asm volatile("s_waitcnt vmcnt(0)" ::: "memory")
#define PRIO1() __builtin_amdgcn_s_setprio(1)
#define PRIO0() __builtin_amdgcn_s_setprio(0)

template<int MODE>
__global__ __launch_bounds__(512, 2) void gemm256(const unsigned short* __restrict__ A,
                                                  const unsigned short* __restrict__ BT,
                                                  const float* __restrict__ bias,
                                                  float* __restrict__ outF,
                                                  unsigned short* __restrict__ outQKV,
                                                  int N, int K) {
  __shared__ char sA[2][32768];   // [256 rows][64 k] bf16, rows 128B, slot^(row&7) swizzle
  __shared__ char sB[2][16384];   // [128 rows][64 k]
  int tid = threadIdx.x;
  int w = tid >> 6, l = tid & 63, g = l >> 4, cx = l & 15;
  int wm = (w >> 1) * 64, wn = (w & 1) * 64;

  // XCD-aware bijective swizzle (nwg % 8 == 0: 768 and 256)
  int nwgx = gridDim.x;
  int nwg = nwgx * gridDim.y;
  int gid = blockIdx.y * nwgx + blockIdx.x;
  int swz = (gid & 7) * (nwg >> 3) + (gid >> 3);
  int bm = (swz / nwgx) * 256, bn = (swz % nwgx) * 128;

  // staging: pre-swizzled global source, linear LDS dest (DMA = uniform base + lane*16)
  int c0 = tid, c1 = tid + 512;
  int ar0 = c0 >> 3, as0 = ((c0 & 7) ^ (ar0 & 7)) * 8;
  int ar1 = c1 >> 3, as1 = ((c1 & 7) ^ (ar1 & 7)) * 8;
  const unsigned short* Ap0 = A + (size_t)(bm + ar0) * K + as0;
  const unsigned short* Ap1 = A + (size_t)(bm + ar1) * K + as1;
  const unsigned short* Bp0 = BT + (size_t)(bn + ar0) * K + as0;
  const unsigned short* Bp1 = BT + (size_t)(bn + ar1) * K + as1;
  const size_t HS = (size_t)128 * K;   // A upper half (rows 128..255) offset

  // staging units: A tile = 4 gloads/thread, B tile = 2 gloads/thread
  #define STAGE_A(t, buf) do { int ko = (t) << 6;                       \
      gload_lds16(Ap0 + ko,      sA[buf] + c0 * 16);                    \
      gload_lds16(Ap1 + ko,      sA[buf] + c1 * 16);                    \
      gload_lds16(Ap0 + HS + ko, sA[buf] + 16384 + c0 * 16);            \
      gload_lds16(Ap1 + HS + ko, sA[buf] + 16384 + c1 * 16); } while (0)
  #define STAGE_B(t, buf) do { int ko = (t) << 6;                       \
      gload_lds16(Bp0 + ko, sB[buf] + c0 * 16);                         \
      gload_lds16(Bp1 + ko, sB[buf] + c1 * 16); } while (0)

  f32x4 acc[4][4];
  #pragma unroll
  for (int i = 0; i < 4; i++)
    #pragma unroll
    for (int j = 0; j < 4; j++) acc[i][j] = (f32x4){0.f, 0.f, 0.f, 0.f};

  int NT = K >> 6;   // K-tiles of 64 (NT = 16 here)

  // prologue: tile0 fully + tile1.A in flight
  STAGE_A(0, 0);
  STAGE_B(0, 0);
  STAGE_A(1, 1);
  VMCNT4();          // t0 landed (6 oldest), t1.A (4) in flight
  BARR();

  int cur = 0;
  for (int t = 0; t < NT; t++) {
    const char* Ac = sA[cur];
    const char* Bc = sB[cur];
    bool h1 = (t + 1) < NT, h2 = (t + 2) < NT;
    bf16x8 af[4][2], bfr[4][2];

    // ---- P0: n-frags 0..1; all A-frags + B01 loaded; prefetch t+1.B ----
    ld_frags<4>(Ac, wm, cx, g, af);
    ld_frags<2>(Bc, wn, cx, g, &bfr[0]);
    if (h1) STAGE_B(t + 1, cur ^ 1);
    BARR(); LGKM0();
    PRIO1(); mfma_pair(af, &bfr[0], acc, 0); PRIO0();
    BARR();

    // ---- P1: n-frags 2..3; prefetch t+2.A into retiring A buffer ----
    // (all reads of sA[cur] completed at P0's second barrier)
    ld_frags<2>(Bc, wn + 32, cx, g, &bfr[2]);
    if (h2) STAGE_A(t + 2, cur);
    BARR(); LGKM0();
    PRIO1(); mfma_pair(af, &bfr[2], acc, 2); PRIO0();
    // boundary: t+1.{A,B} must have landed; keep t+2.A (4 loads) in flight
    if (h2)      { VMCNT4(); }
    else if (h1) { VMCNT0(); }   // final boundary only
    BARR();
    cur ^= 1;
  }

  // epilogue: C/D layout row=(l>>4)*4+r (m-side), col=l&15 (n-side)
  #pragma unroll
  for (int mi = 0; mi < 4; mi++) {
    #pragma unroll
    for (int ni = 0; ni < 4; ni++) {
      int col = bn + wn + ni * 16 + cx;
      float bv = bias[col];
      int row0 = bm + wm + mi * 16 + g * 4;
      #pragma unroll
      for (int r = 0; r < 4; r++) {
        float v = acc[mi][ni][r] + bv;
        int rr = row0 + r;
        if (MODE == 0) {
          outF[(size_t)rr * N + col] = v;
        } else {
          int which = col >> 10, rem = col & 1023;
          int h = rem >> 6, d = rem & 63;
          int b = rr >> 11, cq = rr & 2047;
          if (which == 2) {
            // V: store transposed + kappa-permuted (pure within-32 permutation)
            int pos = (cq & ~31) + (((cq >> 2) & 3) << 3) + (((cq >> 4) & 1) << 2) + (cq & 3);
            outQKV[((size_t)2 * NBH + b * NH + h) * (CSEQ * HD) +
                   (size_t)d * CSEQ + pos] = f2bf(v);
          } else {
            outQKV[((size_t)which * NBH + b * NH + h) * (CSEQ * HD) + (size_t)cq * HD + d] = f2bf(v);
          }
        }
      }
    }
  }
  #undef STAGE_A
  #undef STAGE_B
}

// ---------------- flash attention (causal), swapped-QK^T, register-P ----------------
// 8 waves x 16 q-rows (QBLK=128), KVBLK=128, dbuf, one barrier/iter, XCD-aware
// remap, exp2 softmax, defer-max, global_load_lds DMA staging.
__global__ __launch_bounds__(512, 4) void attn_kernel(const unsigned short* __restrict__ Qb,
                                                      const unsigned short* __restrict__ Kb,
                                                      const unsigned short* __restrict__ VTb,
                                                      unsigned short* __restrict__ O) {
  __shared__ char sKb[2][16384]; // K [128 k][64 d] bf16: slot sp of row holds d-slot sp^(row&7)
  __shared__ char sVt[2][16384]; // V^T [64 d][128 pos] bf16: slot sp of row d holds pos-slot sp^(d&7)
  int tid = threadIdx.x;
  int w = tid >> 6, l = tid & 63, g = l >> 4, cx = l & 15;
  // XCD-aware decode: g%8 == bh&7 -> all 16 qt-blocks of a bh land on one XCD,
  // dispatched consecutively (qt=15 first within each bh for LPT balance).
  int gid = blockIdx.x;
  int bh = ((gid >> 7) << 3) | (gid & 7);
  int qt = 15 - ((gid >> 3) & 15);

  const unsigned short* Qp  = Qb  + (size_t)bh * CSEQ * HD;
  const unsigned short* Kp  = Kb  + (size_t)bh * CSEQ * HD;
  const unsigned short* VTp = VTb + (size_t)bh * CSEQ * HD;  // [64 d][2048 k']

  // Q fragments (B-operand: col=lane&15=q, k=(lane>>4)*8+j), pre-scaled to exp2 domain
  int qrow = qt * 128 + w * 16 + cx;
  bf16x8 qf[2];
  qf[0] = *(const bf16x8*)(Qp + (size_t)qrow * HD + g * 8);
  qf[1] = *(const bf16x8*)(Qp + (size_t)qrow * HD + 32 + g * 8);
  #pragma unroll
  for (int kc = 0; kc < 2; kc++)
    #pragma unroll
    for (int j = 0; j < 8; j++) qf[kc][j] = bf_qscale(qf[kc][j]);

  f32x4 o[4];
  #pragma unroll
  for (int nf2 = 0; nf2 < 4; nf2++) o[nf2] = (f32x4){0.f, 0.f, 0.f, 0.f};
  float mrow = -INFINITY, lrow = 0.f;

  // staging constants (pre-swizzled global source, linear LDS dest)
  int c0 = tid, c1 = tid + 512;
  int krow0 = c0 >> 3, ksl0 = (c0 & 7) ^ (krow0 & 7);
  int krow1 = c1 >> 3, ksl1 = (c1 & 7) ^ (krow1 & 7);
  int vd0 = c0 >> 4, vsl0 = (c0 & 15) ^ (vd0 & 7);
  int vd1 = c1 >> 4, vsl1 = (c1 & 15) ^ (vd1 & 7);
  const unsigned short* Ksrc0 = Kp + (size_t)krow0 * HD + ksl0 * 8;   // += kt*8192
  const unsigned short* Ksrc1 = Kp + (size_t)krow1 * HD + ksl1 * 8;
  const unsigned short* Vsrc0 = VTp + (size_t)vd0 * CSEQ + vsl0 * 8;  // += kt*128
  const unsigned short* Vsrc1 = VTp + (size_t)vd1 * CSEQ + vsl1 * 8;

  // prologue: DMA tile 0 into buf0
  gload_lds16(Ksrc0, sKb[0] + c0 * 16);
  gload_lds16(Ksrc1, sKb[0] + c1 * 16);
  gload_lds16(Vsrc0, sVt[0] + c0 * 16);
  gload_lds16(Vsrc1, sVt[0] + c1 * 16);
  __syncthreads();
  int cur = 0;

  for (int kt = 0; kt <= qt; kt++) {
    if (kt < qt) {  // DMA next tile into buf^1; lands under compute below
      size_t ko = (size_t)(kt + 1) * 128 * HD;
      size_t vo = (size_t)(kt + 1) * 128;
      gload_lds16(Ksrc0 + ko, sKb[cur ^ 1] + c0 * 16);
      gload_lds16(Ksrc1 + ko, sKb[cur ^ 1] + c1 * 16);
      gload_lds16(Vsrc0 + vo, sVt[cur ^ 1] + c0 * 16);
      gload_lds16(Vsrc1 + vo, sVt[cur ^ 1] + c1 * 16);
    }
    const char* Kc = sKb[cur];
    const char* Vc = sVt[cur];

    // ---- S^T = K * Q^T : A = K rows (m = kv idx), B = Q (n = q) ----
    f32x4 sacc[8];
    #pragma unroll
    for (int nf = 0; nf < 8; nf++) sacc[nf] = (f32x4){0.f, 0.f, 0.f, 0.f};
    __builtin_amdgcn_s_setprio(1);
    #pragma unroll
    for (int kc = 0; kc < 2; kc++) {
      #pragma unroll
      for (int nf = 0; nf < 8; nf++) {
        int row = nf * 16 + cx;
        bf16x8 kf = *(const bf16x8*)(Kc + row * 128 + ((((kc << 2) | g) ^ (row & 7)) << 4));
        sacc[nf] = __builtin_amdgcn_mfma_f32_16x16x32_bf16(kf, qf[kc], sacc[nf], 0, 0, 0);
      }
    }
    __builtin_amdgcn_s_setprio(0);

    // lane (g,cx) holds S2[q = w*16+cx][k_local = nf*16 + 4g + r]  (log2 domain)
    if (kt == qt) {  // uniform branch: mask only the diagonal tile
      #pragma unroll
      for (int nf = 0; nf < 8; nf++)
        #pragma unroll
        for (int r = 0; r < 4; r++)
          if (nf * 16 + 4 * g + r > w * 16 + cx) sacc[nf][r] = -INFINITY;
    }
    // 5-deep tree max
    float m8[8];
    #pragma unroll
    for (int nf = 0; nf < 8; nf++)
      m8[nf] = fmaxf(fmaxf(sacc[nf][0], sacc[nf][1]), fmaxf(sacc[nf][2], sacc[nf][3]));
    float mx = fmaxf(fmaxf(fmaxf(m8[0], m8[1]), fmaxf(m8[2], m8[3])),
                     fmaxf(fmaxf(m8[4], m8[5]), fmaxf(m8[6], m8[7])));
    mx = fmaxf(mx, __shfl_xor(mx, 16));
    mx = fmaxf(mx, __shfl_xor(mx, 32));

    // defer-max (T13): skip rescale when per-tile growth <= 8 (p <= 2^8)
    if (!__all(mx - mrow <= 8.f)) {
      float mnew = fmaxf(mrow, mx);
      float alpha = __builtin_amdgcn_exp2f(mrow - mnew);
      mrow = mnew;
      lrow *= alpha;
      #pragma unroll
      for (int r = 0; r < 4; r++) {
        float ar = __shfl(alpha, (l & 48) | ((l >> 2) & 12) | r);
        #pragma unroll
        for (int nf2 = 0; nf2 < 4; nf2++) o[nf2][r] *= ar;
      }
    }
    #pragma unroll
    for (int nf = 0; nf < 8; nf++)
      #pragma unroll
      for (int r = 0; r < 4; r++)
        sacc[nf][r] = __builtin_amdgcn_exp2f(sacc[nf][r] - mrow);
    // 5-deep tree sum
    float s8[8];
    #pragma unroll
    for (int nf = 0; nf < 8; nf++)
      s8[nf] = (sacc[nf][0] + sacc[nf][1]) + (sacc[nf][2] + sacc[nf][3]);
    float sum = ((s8[0] + s8[1]) + (s8[2] + s8[3])) + ((s8[4] + s8[5]) + (s8[6] + s8[7]));
    sum += __shfl_xor(sum, 16);
    sum += __shfl_xor(sum, 32);
    lrow += sum;

    // P -> bf16 A-frags; kc=0..3: elem j carries k = 32kc + 16*(j>=4) + 4g + (j&3)
    bf16x8 pa[4];
    #pragma unroll
    for (int kc = 0; kc < 4; kc++) {
      #pragma unroll
      for (int j = 0; j < 4; j++) {
        pa[kc][j]     = (short)f2bf(sacc[2 * kc][j]);
        pa[kc][j + 4] = (short)f2bf(sacc[2 * kc + 1][j]);
      }
    }

    // ---- O += P * V : B-frag from kappa-ordered V^T rows (contiguous 16B) ----
    __builtin_amdgcn_s_setprio(1);
    #pragma unroll
    for (int kc = 0; kc < 4; kc++) {
      #pragma unroll
      for (int nf2 = 0; nf2 < 4; nf2++) {
        int d = nf2 * 16 + cx;
        bf16x8 vf = *(const bf16x8*)(Vc + ((d * 256 + (((kc << 2) | g) << 4)) ^ ((d & 7) << 4)));
        o[nf2] = __builtin_amdgcn_mfma_f32_16x16x32_bf16(pa[kc], vf, o[nf2], 0, 0, 0);
      }
    }
    __builtin_amdgcn_s_setprio(0);

    if (kt < qt) {   // single barrier per iter: drains this wave's DMAs + LDS reads
      __syncthreads();
      cur ^= 1;
    }
  }

  // epilogue: lane (g,cx): O rows q = 4g+r, cols d = nf2*16+cx
  int b = bh >> 4, h = bh & 15;
  float linv = 1.0f / lrow;
  #pragma unroll
  for (int r = 0; r < 4; r++) {
    float inv = __shfl(linv, (l & 48) | ((l >> 2) & 12) | r);
    int q = qt * 128 + w * 16 + 4 * g + r;
    size_t base = ((size_t)(b * CSEQ + q)) * DM + h * HD;
    #pragma unroll
    for (int nf2 = 0; nf2 < 4; nf2++)
      O[base + nf2 * 16 + cx] = f2bf(o[nf2][r] * inv);
  }
}

// ---------------- launch ----------------
extern "C" void kernel_launch(void* const* d_in, const int* in_sizes, int n_in,
                              void* d_out, int out_size, void* d_ws, size_t ws_size,
                              hipStream_t stream) {
  const float* x    = (const float*)d_in[0];
  const float* Wqkv = (const float*)d_in[1];
  const float* bqkv = (const float*)d_in[2];
  const float* Wo   = (const float*)d_in[3];
  const float* bo   = (const float*)d_in[4];
  float* out = (float*)d_out;

  unsigned short* ws = (unsigned short*)d_ws;
  const size_t XB_OFF    = 0;                     // x bf16 [8192][1024]
  const size_t WQKVT_OFF = 8388608;               // Wqkv^T bf16 [3072][1024]
  const size_t WOT_OFF   = WQKVT_OFF + 3145728;   // Wo^T bf16 [1024][1024]
  const size_t QKV_OFF   = WOT_OFF + 1048576;     // Q,K [bh][k][d]; V^T [bh][d][k']
  const size_t ATT_OFF   = QKV_OFF + 3 * 8388608; // att out bf16 [8192][1024]

  unsigned short* xb    = ws + XB_OFF;
  unsigned short* wqkvT = ws + WQKVT_OFF;
  unsigned short* woT   = ws + WOT_OFF;
  unsigned short* qkv   = ws + QKV_OFF;
  unsigned short* att   = ws + ATT_OFF;

  cast_f32_bf16<<<2048, 256, 0, stream>>>(x, xb, (MROWS * DM) / 4);
  transpose_cast<<<dim3(3 * DM / 32, DM / 32), dim3(32, 8), 0, stream>>>(Wqkv, wqkvT, DM, 3 * DM);
  transpose_cast<<<dim3(DM / 32, DM / 32), dim3(32, 8), 0, stream>>>(Wo, woT, DM, DM);

  // BN=128: QKV grid 24x32 = 768 blocks (3 exact rounds), proj 8x32 = 256 (1 round)
  gemm256<1><<<dim3(3 * DM / 128, MROWS / 256), 512, 0, stream>>>(
      xb, wqkvT, bqkv, nullptr, qkv, 3 * DM, DM);

  attn_kernel<<<dim3(1024), 512, 0, stream>>>(
      qkv, qkv + 8388608, qkv + 16777216, att);

  gemm256<0><<<dim3(DM / 128, MROWS / 256), 512, 0, stream>>>(
      att, woT, bo, out, nullptr, DM, DM);
}

// Round 3
// 197.012 us; speedup vs baseline: 1.1420x; 1.0223x over previous
//
#include <hip/hip_runtime.h>
#include <hip/hip_bf16.h>

typedef __attribute__((ext_vector_type(8))) short bf16x8;
typedef __attribute__((ext_vector_type(4))) float f32x4;

#define NH 16
#define DM 1024
#define HD 64
#define CSEQ 2048
#define MROWS 8192   // B*C
#define NBH 64       // B*NH

static __device__ __forceinline__ unsigned short f2bf(float f) {
  __hip_bfloat16 h = __float2bfloat16(f);
  return *reinterpret_cast<unsigned short*>(&h);
}

static __device__ __forceinline__ short bf_qscale(short s) {
  // fold attn scale (1/8) and log2(e) into Q: S*0.125*1.4427 -> exp2 domain
  unsigned u = ((unsigned)(unsigned short)s) << 16;
  float f = __builtin_bit_cast(float, u) * 0.18033688f;
  return (short)f2bf(f);
}

static __device__ __forceinline__ void gload_lds16(const void* g, void* l) {
  __builtin_amdgcn_global_load_lds(
      (const __attribute__((address_space(1))) unsigned int*)g,
      (__attribute__((address_space(3))) unsigned int*)l, 16, 0, 0);
}

// ---------------- cast fp32 -> bf16 (vectorized x4) ----------------
__global__ __launch_bounds__(256) void cast_f32_bf16(const float* __restrict__ in,
                                                     unsigned short* __restrict__ out,
                                                     int n4) {
  int stride = gridDim.x * blockDim.x;
  for (int i = blockIdx.x * blockDim.x + threadIdx.x; i < n4; i += stride) {
    float4 v = ((const float4*)in)[i];
    ushort4 o;
    o.x = f2bf(v.x); o.y = f2bf(v.y); o.z = f2bf(v.z); o.w = f2bf(v.w);
    ((ushort4*)out)[i] = o;
  }
}

// ---------------- transpose + cast: src[K][N] fp32 -> dst[N][K] bf16 ----------------
__global__ __launch_bounds__(256) void transpose_cast(const float* __restrict__ src,
                                                      unsigned short* __restrict__ dst,
                                                      int K, int N) {
  __shared__ float tile[32][33];
  int tx = threadIdx.x, ty = threadIdx.y;
  int n0 = blockIdx.x * 32, k0 = blockIdx.y * 32;
  #pragma unroll
  for (int i = 0; i < 32; i += 8)
    tile[ty + i][tx] = src[(size_t)(k0 + ty + i) * N + n0 + tx];
  __syncthreads();
  #pragma unroll
  for (int i = 0; i < 32; i += 8)
    dst[(size_t)(n0 + ty + i) * K + k0 + tx] = f2bf(tile[tx][ty + i]);
}

// ===================== 128x128 bf16 GEMM, 2 blocks/CU =====================
// C = A[M][K] * BT[N][K]^T + bias.  4 waves (2Mx2N), per-wave 64x64 out, BK=64,
// 64KB LDS double-buffer -> 2 blocks/CU (8 waves/CU = 4 waves/SIMD): one
// block's MFMA covers the other's barrier/staging stalls (m114 overlap).
// P0: issue ALL 16 frag ds_reads -> lgkm0 -> 16 MFMA.  P1: stage tile t+2
// (A+B, 8 gloads) into the fully-retired current buffer, 16 MFMA with zero
// LDS waits, boundary vmcnt(8) keeps t+2's 8 loads in flight (never 0 until
// the final boundary).  Every prefetch window = one full K-tile.
// Grid: QKV 24x64=1536 blocks (3 exact rounds of 512 slots), proj 8x64=512
// (1 exact round).  XOR-swizzled LDS rows (slot ^ (row&7)) via pre-swizzled
// global source + linear DMA dest.
// MODE 0: write fp32 out[M][N].
// MODE 1: scatter bf16 into Q,K [bh][cq][d]; V transposed+kappa-permuted.

template<int CNT>
static __device__ __forceinline__ void ld_frags(const char* base, int r0, int cx, int g,
                                                bf16x8 (*out)[2]) {
  #pragma unroll
  for (int i = 0; i < CNT; i++) {
    int row = r0 + i * 16 + cx;
    #pragma unroll
    for (int kc = 0; kc < 2; kc++)
      out[i][kc] = *(const bf16x8*)(base + row * 128 + ((((kc << 2) | g) ^ (row & 7)) << 4));
  }
}

static __device__ __forceinline__ void mfma_pair(const bf16x8 af[4][2], const bf16x8 bf2[2][2],
                                                 f32x4 acc[4][4], int n0) {
  #pragma unroll
  for (int kc = 0; kc < 2; kc++)
    #pragma unroll
    for (int mi = 0; mi < 4; mi++)
      #pragma unroll
      for (int ni = 0; ni < 2; ni++)
        acc[mi][n0 + ni] = __builtin_amdgcn_mfma_f32_16x16x32_bf16(
            af[mi][kc], bf2[ni][kc], acc[mi][n0 + ni], 0, 0, 0);
}

#define BARR() __builtin_amdgcn_s_barrier()
#define LGKM0() asm volatile("s_waitcnt lgkmcnt(0)" ::: "memory")
#define VMCNT8() asm volatile("s_waitcnt vmcnt(8)" ::: "memory")
#define VMCNT0() asm volatile("s_waitcnt vmcnt(0)" ::: "memory")
#define PRIO1() __builtin_amdgcn_s_setprio(1)
#define PRIO0() __builtin_amdgcn_s_setprio(0)

template<int MODE>
__global__ __launch_bounds__(256, 2) void gemm128d(const unsigned short* __restrict__ A,
                                                   const unsigned short* __restrict__ BT,
                                                   const float* __restrict__ bias,
                                                   float* __restrict__ outF,
                                                   unsigned short* __restrict__ outQKV,
                                                   int N, int K) {
  __shared__ char sA[2][16384];   // [128 rows][64 k] bf16, rows 128B, slot^(row&7) swizzle
  __shared__ char sB[2][16384];
  int tid = threadIdx.x;
  int w = tid >> 6, l = tid & 63, g = l >> 4, cx = l & 15;
  int wm = (w >> 1) * 64, wn = (w & 1) * 64;

  // XCD-aware bijective swizzle (nwg % 8 == 0: 1536 and 512)
  int nwgx = gridDim.x;
  int nwg = nwgx * gridDim.y;
  int gid = blockIdx.y * nwgx + blockIdx.x;
  int swz = (gid & 7) * (nwg >> 3) + (gid >> 3);
  int bm = (swz / nwgx) * 128, bn = (swz % nwgx) * 128;

  // staging: pre-swizzled global source, linear LDS dest (DMA = uniform base + lane*16)
  // tile = 128 rows x 64 k x 2B = 16KB = 1024 lane-chunks of 16B; 256 thr -> 4 chunks each
  const unsigned short* Ap[4];
  const unsigned short* Bp[4];
  #pragma unroll
  for (int i = 0; i < 4; i++) {
    int c = tid + i * 256;
    int ar = c >> 3, as = ((c & 7) ^ (ar & 7)) * 8;
    Ap[i] = A + (size_t)(bm + ar) * K + as;
    Bp[i] = BT + (size_t)(bn + ar) * K + as;
  }

  #define STAGE_AB(t, buf) do { int ko_ = (t) << 6;                 \
      gload_lds16(Ap[0] + ko_, sA[buf] + (tid)       * 16);         \
      gload_lds16(Ap[1] + ko_, sA[buf] + (tid + 256) * 16);         \
      gload_lds16(Ap[2] + ko_, sA[buf] + (tid + 512) * 16);         \
      gload_lds16(Ap[3] + ko_, sA[buf] + (tid + 768) * 16);         \
      gload_lds16(Bp[0] + ko_, sB[buf] + (tid)       * 16);         \
      gload_lds16(Bp[1] + ko_, sB[buf] + (tid + 256) * 16);         \
      gload_lds16(Bp[2] + ko_, sB[buf] + (tid + 512) * 16);         \
      gload_lds16(Bp[3] + ko_, sB[buf] + (tid + 768) * 16);         \
    } while (0)

  f32x4 acc[4][4];
  #pragma unroll
  for (int i = 0; i < 4; i++)
    #pragma unroll
    for (int j = 0; j < 4; j++) acc[i][j] = (f32x4){0.f, 0.f, 0.f, 0.f};

  int NT = K >> 6;   // K-tiles of 64 (NT = 16 here)

  // prologue: tile0 -> buf0, tile1 -> buf1 (stays in flight)
  STAGE_AB(0, 0);
  STAGE_AB(1, 1);
  VMCNT8();          // t0 landed (8 oldest), t1 (8) in flight
  BARR();

  int cur = 0;
  for (int t = 0; t < NT; t++) {
    const char* Ac = sA[cur];
    const char* Bc = sB[cur];
    bool h1 = (t + 1) < NT, h2 = (t + 2) < NT;
    bf16x8 af[4][2], bfr[4][2];

    // ---- P0: ALL frag reads (16 b128), then first MFMA half ----
    ld_frags<4>(Ac, wm, cx, g, af);
    ld_frags<4>(Bc, wn, cx, g, bfr);
    BARR(); LGKM0();
    PRIO1(); mfma_pair(af, &bfr[0], acc, 0); PRIO0();
    BARR();
    // both sA[cur] and sB[cur] fully consumed by every wave at this point

    // ---- P1: stage tile t+2 into the retired buffer; MFMA half 2 (no LDS waits) ----
    if (h2) STAGE_AB(t + 2, cur);
    PRIO1(); mfma_pair(af, &bfr[2], acc, 2); PRIO0();
    // boundary: t+1 (8 loads) must have landed; keep t+2's 8 in flight
    if (h2)      { VMCNT8(); }
    else if (h1) { VMCNT0(); }   // final boundary only
    BARR();
    cur ^= 1;
  }

  // epilogue: C/D layout row=(l>>4)*4+r (m-side), col=l&15 (n-side)
  #pragma unroll
  for (int mi = 0; mi < 4; mi++) {
    #pragma unroll
    for (int ni = 0; ni < 4; ni++) {
      int col = bn + wn + ni * 16 + cx;
      float bv = bias[col];
      int row0 = bm + wm + mi * 16 + g * 4;
      #pragma unroll
      for (int r = 0; r < 4; r++) {
        float v = acc[mi][ni][r] + bv;
        int rr = row0 + r;
        if (MODE == 0) {
          outF[(size_t)rr * N + col] = v;
        } else {
          int which = col >> 10, rem = col & 1023;
          int h = rem >> 6, d = rem & 63;
          int b = rr >> 11, cq = rr & 2047;
          if (which == 2) {
            // V: store transposed + kappa-permuted (pure within-32 permutation)
            int pos = (cq & ~31) + (((cq >> 2) & 3) << 3) + (((cq >> 4) & 1) << 2) + (cq & 3);
            outQKV[((size_t)2 * NBH + b * NH + h) * (CSEQ * HD) +
                   (size_t)d * CSEQ + pos] = f2bf(v);
          } else {
            outQKV[((size_t)which * NBH + b * NH + h) * (CSEQ * HD) + (size_t)cq * HD + d] = f2bf(v);
          }
        }
      }
    }
  }
  #undef STAGE_AB
}

// ---------------- flash attention (causal), swapped-QK^T, register-P ----------------
// 8 waves x 16 q-rows (QBLK=128), KVBLK=128, dbuf, one barrier/iter, XCD-aware
// remap, exp2 softmax, defer-max, global_load_lds DMA staging.
__global__ __launch_bounds__(512, 4) void attn_kernel(const unsigned short* __restrict__ Qb,
                                                      const unsigned short* __restrict__ Kb,
                                                      const unsigned short* __restrict__ VTb,
                                                      unsigned short* __restrict__ O) {
  __shared__ char sKb[2][16384]; // K [128 k][64 d] bf16: slot sp of row holds d-slot sp^(row&7)
  __shared__ char sVt[2][16384]; // V^T [64 d][128 pos] bf16: slot sp of row d holds pos-slot sp^(d&7)
  int tid = threadIdx.x;
  int w = tid >> 6, l = tid & 63, g = l >> 4, cx = l & 15;
  // XCD-aware decode: g%8 == bh&7 -> all 16 qt-blocks of a bh land on one XCD,
  // dispatched consecutively (qt=15 first within each bh for LPT balance).
  int gid = blockIdx.x;
  int bh = ((gid >> 7) << 3) | (gid & 7);
  int qt = 15 - ((gid >> 3) & 15);

  const unsigned short* Qp  = Qb  + (size_t)bh * CSEQ * HD;
  const unsigned short* Kp  = Kb  + (size_t)bh * CSEQ * HD;
  const unsigned short* VTp = VTb + (size_t)bh * CSEQ * HD;  // [64 d][2048 k']

  // Q fragments (B-operand: col=lane&15=q, k=(lane>>4)*8+j), pre-scaled to exp2 domain
  int qrow = qt * 128 + w * 16 + cx;
  bf16x8 qf[2];
  qf[0] = *(const bf16x8*)(Qp + (size_t)qrow * HD + g * 8);
  qf[1] = *(const bf16x8*)(Qp + (size_t)qrow * HD + 32 + g * 8);
  #pragma unroll
  for (int kc = 0; kc < 2; kc++)
    #pragma unroll
    for (int j = 0; j < 8; j++) qf[kc][j] = bf_qscale(qf[kc][j]);

  f32x4 o[4];
  #pragma unroll
  for (int nf2 = 0; nf2 < 4; nf2++) o[nf2] = (f32x4){0.f, 0.f, 0.f, 0.f};
  float mrow = -INFINITY, lrow = 0.f;

  // staging constants (pre-swizzled global source, linear LDS dest)
  int c0 = tid, c1 = tid + 512;
  int krow0 = c0 >> 3, ksl0 = (c0 & 7) ^ (krow0 & 7);
  int krow1 = c1 >> 3, ksl1 = (c1 & 7) ^ (krow1 & 7);
  int vd0 = c0 >> 4, vsl0 = (c0 & 15) ^ (vd0 & 7);
  int vd1 = c1 >> 4, vsl1 = (c1 & 15) ^ (vd1 & 7);
  const unsigned short* Ksrc0 = Kp + (size_t)krow0 * HD + ksl0 * 8;   // += kt*8192
  const unsigned short* Ksrc1 = Kp + (size_t)krow1 * HD + ksl1 * 8;
  const unsigned short* Vsrc0 = VTp + (size_t)vd0 * CSEQ + vsl0 * 8;  // += kt*128
  const unsigned short* Vsrc1 = VTp + (size_t)vd1 * CSEQ + vsl1 * 8;

  // prologue: DMA tile 0 into buf0
  gload_lds16(Ksrc0, sKb[0] + c0 * 16);
  gload_lds16(Ksrc1, sKb[0] + c1 * 16);
  gload_lds16(Vsrc0, sVt[0] + c0 * 16);
  gload_lds16(Vsrc1, sVt[0] + c1 * 16);
  __syncthreads();
  int cur = 0;

  for (int kt = 0; kt <= qt; kt++) {
    if (kt < qt) {  // DMA next tile into buf^1; lands under compute below
      size_t ko = (size_t)(kt + 1) * 128 * HD;
      size_t vo = (size_t)(kt + 1) * 128;
      gload_lds16(Ksrc0 + ko, sKb[cur ^ 1] + c0 * 16);
      gload_lds16(Ksrc1 + ko, sKb[cur ^ 1] + c1 * 16);
      gload_lds16(Vsrc0 + vo, sVt[cur ^ 1] + c0 * 16);
      gload_lds16(Vsrc1 + vo, sVt[cur ^ 1] + c1 * 16);
    }
    const char* Kc = sKb[cur];
    const char* Vc = sVt[cur];

    // ---- S^T = K * Q^T : A = K rows (m = kv idx), B = Q (n = q) ----
    f32x4 sacc[8];
    #pragma unroll
    for (int nf = 0; nf < 8; nf++) sacc[nf] = (f32x4){0.f, 0.f, 0.f, 0.f};
    __builtin_amdgcn_s_setprio(1);
    #pragma unroll
    for (int kc = 0; kc < 2; kc++) {
      #pragma unroll
      for (int nf = 0; nf < 8; nf++) {
        int row = nf * 16 + cx;
        bf16x8 kf = *(const bf16x8*)(Kc + row * 128 + ((((kc << 2) | g) ^ (row & 7)) << 4));
        sacc[nf] = __builtin_amdgcn_mfma_f32_16x16x32_bf16(kf, qf[kc], sacc[nf], 0, 0, 0);
      }
    }
    __builtin_amdgcn_s_setprio(0);

    // lane (g,cx) holds S2[q = w*16+cx][k_local = nf*16 + 4g + r]  (log2 domain)
    if (kt == qt) {  // uniform branch: mask only the diagonal tile
      #pragma unroll
      for (int nf = 0; nf < 8; nf++)
        #pragma unroll
        for (int r = 0; r < 4; r++)
          if (nf * 16 + 4 * g + r > w * 16 + cx) sacc[nf][r] = -INFINITY;
    }
    // 5-deep tree max
    float m8[8];
    #pragma unroll
    for (int nf = 0; nf < 8; nf++)
      m8[nf] = fmaxf(fmaxf(sacc[nf][0], sacc[nf][1]), fmaxf(sacc[nf][2], sacc[nf][3]));
    float mx = fmaxf(fmaxf(fmaxf(m8[0], m8[1]), fmaxf(m8[2], m8[3])),
                     fmaxf(fmaxf(m8[4], m8[5]), fmaxf(m8[6], m8[7])));
    mx = fmaxf(mx, __shfl_xor(mx, 16));
    mx = fmaxf(mx, __shfl_xor(mx, 32));

    // defer-max (T13): skip rescale when per-tile growth <= 8 (p <= 2^8)
    if (!__all(mx - mrow <= 8.f)) {
      float mnew = fmaxf(mrow, mx);
      float alpha = __builtin_amdgcn_exp2f(mrow - mnew);
      mrow = mnew;
      lrow *= alpha;
      #pragma unroll
      for (int r = 0; r < 4; r++) {
        float ar = __shfl(alpha, (l & 48) | ((l >> 2) & 12) | r);
        #pragma unroll
        for (int nf2 = 0; nf2 < 4; nf2++) o[nf2][r] *= ar;
      }
    }
    #pragma unroll
    for (int nf = 0; nf < 8; nf++)
      #pragma unroll
      for (int r = 0; r < 4; r++)
        sacc[nf][r] = __builtin_amdgcn_exp2f(sacc[nf][r] - mrow);
    // 5-deep tree sum
    float s8[8];
    #pragma unroll
    for (int nf = 0; nf < 8; nf++)
      s8[nf] = (sacc[nf][0] + sacc[nf][1]) + (sacc[nf][2] + sacc[nf][3]);
    float sum = ((s8[0] + s8[1]) + (s8[2] + s8[3])) + ((s8[4] + s8[5]) + (s8[6] + s8[7]));
    sum += __shfl_xor(sum, 16);
    sum += __shfl_xor(sum, 32);
    lrow += sum;

    // P -> bf16 A-frags; kc=0..3: elem j carries k = 32kc + 16*(j>=4) + 4g + (j&3)
    bf16x8 pa[4];
    #pragma unroll
    for (int kc = 0; kc < 4; kc++) {
      #pragma unroll
      for (int j = 0; j < 4; j++) {
        pa[kc][j]     = (short)f2bf(sacc[2 * kc][j]);
        pa[kc][j + 4] = (short)f2bf(sacc[2 * kc + 1][j]);
      }
    }

    // ---- O += P * V : B-frag from kappa-ordered V^T rows (contiguous 16B) ----
    __builtin_amdgcn_s_setprio(1);
    #pragma unroll
    for (int kc = 0; kc < 4; kc++) {
      #pragma unroll
      for (int nf2 = 0; nf2 < 4; nf2++) {
        int d = nf2 * 16 + cx;
        bf16x8 vf = *(const bf16x8*)(Vc + ((d * 256 + (((kc << 2) | g) << 4)) ^ ((d & 7) << 4)));
        o[nf2] = __builtin_amdgcn_mfma_f32_16x16x32_bf16(pa[kc], vf, o[nf2], 0, 0, 0);
      }
    }
    __builtin_amdgcn_s_setprio(0);

    if (kt < qt) {   // single barrier per iter: drains this wave's DMAs + LDS reads
      __syncthreads();
      cur ^= 1;
    }
  }

  // epilogue: lane (g,cx): O rows q = 4g+r, cols d = nf2*16+cx
  int b = bh >> 4, h = bh & 15;
  float linv = 1.0f / lrow;
  #pragma unroll
  for (int r = 0; r < 4; r++) {
    float inv = __shfl(linv, (l & 48) | ((l >> 2) & 12) | r);
    int q = qt * 128 + w * 16 + 4 * g + r;
    size_t base = ((size_t)(b * CSEQ + q)) * DM + h * HD;
    #pragma unroll
    for (int nf2 = 0; nf2 < 4; nf2++)
      O[base + nf2 * 16 + cx] = f2bf(o[nf2][r] * inv);
  }
}

// ---------------- launch ----------------
extern "C" void kernel_launch(void* const* d_in, const int* in_sizes, int n_in,
                              void* d_out, int out_size, void* d_ws, size_t ws_size,
                              hipStream_t stream) {
  const float* x    = (const float*)d_in[0];
  const float* Wqkv = (const float*)d_in[1];
  const float* bqkv = (const float*)d_in[2];
  const float* Wo   = (const float*)d_in[3];
  const float* bo   = (const float*)d_in[4];
  float* out = (float*)d_out;

  unsigned short* ws = (unsigned short*)d_ws;
  const size_t XB_OFF    = 0;                     // x bf16 [8192][1024]
  const size_t WQKVT_OFF = 8388608;               // Wqkv^T bf16 [3072][1024]
  const size_t WOT_OFF   = WQKVT_OFF + 3145728;   // Wo^T bf16 [1024][1024]
  const size_t QKV_OFF   = WOT_OFF + 1048576;     // Q,K [bh][k][d]; V^T [bh][d][k']
  const size_t ATT_OFF   = QKV_OFF + 3 * 8388608; // att out bf16 [8192][1024]

  unsigned short* xb    = ws + XB_OFF;
  unsigned short* wqkvT = ws + WQKVT_OFF;
  unsigned short* woT   = ws + WOT_OFF;
  unsigned short* qkv   = ws + QKV_OFF;
  unsigned short* att   = ws + ATT_OFF;

  cast_f32_bf16<<<2048, 256, 0, stream>>>(x, xb, (MROWS * DM) / 4);
  transpose_cast<<<dim3(3 * DM / 32, DM / 32), dim3(32, 8), 0, stream>>>(Wqkv, wqkvT, DM, 3 * DM);
  transpose_cast<<<dim3(DM / 32, DM / 32), dim3(32, 8), 0, stream>>>(Wo, woT, DM, DM);

  // 128x128 tile, 2 blocks/CU: QKV 24x64 = 1536 blocks (3 rounds of 512),
  // proj 8x64 = 512 blocks (1 exact round)
  gemm128d<1><<<dim3(3 * DM / 128, MROWS / 128), 256, 0, stream>>>(
      xb, wqkvT, bqkv, nullptr, qkv, 3 * DM, DM);

  attn_kernel<<<dim3(1024), 512, 0, stream>>>(
      qkv, qkv + 8388608, qkv + 16777216, att);

  gemm128d<0><<<dim3(DM / 128, MROWS / 128), 256, 0, stream>>>(
      att, woT, bo, out, nullptr, DM, DM);
}